// Round 11
// baseline (215.810 us; speedup 1.0000x reference)
//
#include <hip/hip_runtime.h>

// FIR 4x4 separable depthwise filter, k1=[1,3,3,1], k2=outer(k1,k1)/64.
// Input x: (8, 64, 512, 512) f32 -> 512 planes of 512x512.
// lax SAME padding: pad_lo=1, pad_hi=2 (zeros).
// out[r][c] = (1/64) * (H[r-1][c] + 3*H[r][c] + 3*H[r+1][c] + H[r+2][c])
//   H[y][c] = x[y][c-1] + 3*x[y][c] + 3*x[y][c+1] + x[y][c+2]
//
// R11 = R10 (4 floats/lane, 256-col half-row per wave, all loads/stores
// dwordx4 over contiguous 1 KB spans, 3 shuffles/row, 2 planes/wave,
// NT full-line stores: -3.6% in R10) with two read-side changes:
//  (1) FIR_ROWS 32 -> 64: halo re-reads 9.4% -> 4.7% (~25 MB less fetch);
//      R7 proved strip size has no occupancy cost here.
//  (2) NT loads on the two main row loads (pure stream, read-~once);
//      seam loads stay cached (tiny, reused across lanes).

#define FIR_W 512
#define FIR_H 512
#define FIR_ROWS 64   // rows per wave-strip
#define PLANE_SZ ((size_t)FIR_W * FIR_H)

typedef float fvec4 __attribute__((ext_vector_type(4)));  // native vec for nt ops

__device__ __forceinline__ void nt_store4(float* addr, float4 v) {
    fvec4 n = {v.x, v.y, v.z, v.w};
    __builtin_nontemporal_store(n, reinterpret_cast<fvec4*>(addr));
}

__device__ __forceinline__ float4 nt_load4(const float* addr) {
    fvec4 n = __builtin_nontemporal_load(reinterpret_cast<const fvec4*>(addr));
    float4 v; v.x = n.x; v.y = n.y; v.z = n.z; v.w = n.w;
    return v;
}

__device__ __forceinline__ float4 fir_hfilt(float4 v, float4 s, int lane) {
    float xm1 = __shfl_up(v.w, 1);     // col c-1
    float xp4 = __shfl_down(v.x, 1);   // col c+4
    float xp5 = __shfl_down(v.y, 1);   // col c+5
    if (lane == 0)  xm1 = s.w;                 // seam or zero-pad
    if (lane == 63) { xp4 = s.x; xp5 = s.y; }  // seam or zero-pad
    float4 h;
    h.x = xm1 + 3.0f * (v.x + v.y) + v.z;
    h.y = v.x + 3.0f * (v.y + v.z) + v.w;
    h.z = v.y + 3.0f * (v.z + v.w) + xp4;
    h.w = v.z + 3.0f * (v.w + xp4) + xp5;
    return h;
}

// Load row y of both planes (and seam fragments), then filter both.
__device__ __forceinline__ void fir_hrow2(const float* __restrict__ pA,
                                          const float* __restrict__ pB,
                                          int y, int lane, int c0,
                                          float4& hA, float4& hB) {
    if ((unsigned)y >= FIR_H) {   // wave-uniform
        hA.x = hA.y = hA.z = hA.w = 0.0f;
        hB = hA;
        return;
    }
    const size_t rowoff = (size_t)y * FIR_W;
    const float* rowA = pA + rowoff;
    const float* rowB = pB + rowoff;
    const float4 vA = nt_load4(rowA + c0 + 4 * lane);
    const float4 vB = nt_load4(rowB + c0 + 4 * lane);

    // Seam values from the other half-row (<=1 active lane per plane).
    float4 sA, sB;
    sA.x = sA.y = sA.z = sA.w = 0.0f;
    sB = sA;
    if (lane == 0 && c0 != 0) {
        sA = *reinterpret_cast<const float4*>(rowA + c0 - 4);
        sB = *reinterpret_cast<const float4*>(rowB + c0 - 4);
    }
    if (lane == 63 && c0 == 0) {
        sA = *reinterpret_cast<const float4*>(rowA + 256);
        sB = *reinterpret_cast<const float4*>(rowB + 256);
    }

    hA = fir_hfilt(vA, sA, lane);
    hB = fir_hfilt(vB, sB, lane);
}

__device__ __forceinline__ float4 fir_vcomb(float4 h0, float4 h1, float4 h2, float4 h3) {
    const float s = 1.0f / 64.0f;
    float4 o;
    o.x = (h0.x + h3.x + 3.0f * (h1.x + h2.x)) * s;
    o.y = (h0.y + h3.y + 3.0f * (h1.y + h2.y)) * s;
    o.z = (h0.z + h3.z + 3.0f * (h1.z + h2.z)) * s;
    o.w = (h0.w + h3.w + 3.0f * (h1.w + h2.w)) * s;
    return o;
}

__global__ __launch_bounds__(256, 4) void FIRFilter_88579405512825_kernel(
        const float* __restrict__ x, float* __restrict__ out) {
    const int lane = threadIdx.x;                             // 0..63: 4 cols each
    const int w    = blockIdx.x * blockDim.y + threadIdx.y;   // 0..15: wave task
    const int half  = w & 1;                                  // half-row panel
    const int strip = w >> 1;                                 // 64-row strip
    const int pp    = blockIdx.y;                             // 0..255: plane pair
    const int c0 = half * 256;

    const float* pA = x + (size_t)(2 * pp) * PLANE_SZ;
    const float* pB = pA + PLANE_SZ;
    float* qA = out + (size_t)(2 * pp) * PLANE_SZ;
    float* qB = qA + PLANE_SZ;

    const int r0 = strip * FIR_ROWS;

    // Rolling windows (per plane): need H(r-1..r+2) for output row r.
    float4 a1, a2, a3, b1, b2, b3;
    fir_hrow2(pA, pB, r0 - 1, lane, c0, a1, b1);
    fir_hrow2(pA, pB, r0,     lane, c0, a2, b2);
    fir_hrow2(pA, pB, r0 + 1, lane, c0, a3, b3);

    #pragma unroll 4
    for (int r = r0; r < r0 + FIR_ROWS; ++r) {
        float4 a0 = a1; a1 = a2; a2 = a3;
        float4 b0 = b1; b1 = b2; b2 = b3;
        fir_hrow2(pA, pB, r + 2, lane, c0, a3, b3);

        const size_t off = (size_t)r * FIR_W + c0 + 4 * lane;
        nt_store4(qA + off, fir_vcomb(a0, a1, a2, a3));
        nt_store4(qB + off, fir_vcomb(b0, b1, b2, b3));
    }
}

extern "C" void kernel_launch(void* const* d_in, const int* in_sizes, int n_in,
                              void* d_out, int out_size, void* d_ws, size_t ws_size,
                              hipStream_t stream) {
    const float* x = (const float*)d_in[0];
    float* out = (float*)d_out;

    const int planes = in_sizes[0] / (FIR_W * FIR_H);   // 8*64 = 512

    // block: 64 lanes x 4 waves = 256 threads; 16 wave-tasks per plane-pair
    // (2 half-row panels x 8 strips of 64 rows) -> grid.x = 4.
    dim3 block(64, 4);
    dim3 grid(4, planes / 2);

    FIRFilter_88579405512825_kernel<<<grid, block, 0, stream>>>(x, out);
}

// Round 12
// 214.113 us; speedup vs baseline: 1.0079x; 1.0079x over previous
//
#include <hip/hip_runtime.h>

// FIR 4x4 separable depthwise filter, k1=[1,3,3,1], k2=outer(k1,k1)/64.
// Input x: (8, 64, 512, 512) f32 -> 512 planes of 512x512.
// lax SAME padding: pad_lo=1, pad_hi=2 (zeros).
// out[r][c] = (1/64) * (H[r-1][c] + 3*H[r][c] + 3*H[r+1][c] + H[r+2][c])
//   H[y][c] = x[y][c-1] + 3*x[y][c] + 3*x[y][c+1] + x[y][c+2]
//
// FINAL (= R10, best measured: 214.7 us ~= 83% of the 6.29 TB/s copy
// ceiling at ~1.1 GB real HBM traffic):
//  - 4 floats/lane; one wave owns a 256-col half-row; every load and store
//    is one dwordx4 over a contiguous 1 KB span (8 fully-covered 128 B
//    lines per wave-store -> zero write amplification; R5 measured 1.5x
//    with the 8-float/lane half-line layout).
//  - 3 shuffles/row for the column halo (R6: 9 shuffles/row cost more
//    than perfect store coalescing saved).
//  - 2 independent planes per wave (MLP; R9: neutral but keeps VMEM
//    batched 2-at-a-time).
//  - NONTEMPORAL stores on full-line stores: -3.6% (R10). Writes stream
//    without L3 write-allocate, freeing L3 for the input. (R4 showed NT on
//    HALF-line stores is a 2x WRITE_SIZE disaster - RMW at the MC.)
//  - Cached (non-NT) loads: R11 showed NT loads + 64-row strips are
//    slightly worse (halo reuse between strips needs L2/L3 residency).
//  - FIR_ROWS=32, grid 8 x 256: 100% static occupancy available (R7
//    proved occupancy >41% doesn't matter; this costs nothing).
// Falsified levers: VMEM instr count (R1), R/W turnaround (R3/R5), store
// coalescing (R6/R8), occupancy (R7), per-wave MLP (R9), explicit SW
// pipeline (R5), NT loads / halo reduction (R11).

#define FIR_W 512
#define FIR_H 512
#define FIR_ROWS 32   // rows per wave-strip
#define PLANE_SZ ((size_t)FIR_W * FIR_H)

typedef float fvec4 __attribute__((ext_vector_type(4)));  // native vec for nt-store

__device__ __forceinline__ void nt_store4(float* addr, float4 v) {
    fvec4 n = {v.x, v.y, v.z, v.w};
    __builtin_nontemporal_store(n, reinterpret_cast<fvec4*>(addr));
}

__device__ __forceinline__ float4 fir_hfilt(float4 v, float4 s, int lane) {
    float xm1 = __shfl_up(v.w, 1);     // col c-1
    float xp4 = __shfl_down(v.x, 1);   // col c+4
    float xp5 = __shfl_down(v.y, 1);   // col c+5
    if (lane == 0)  xm1 = s.w;                 // seam or zero-pad
    if (lane == 63) { xp4 = s.x; xp5 = s.y; }  // seam or zero-pad
    float4 h;
    h.x = xm1 + 3.0f * (v.x + v.y) + v.z;
    h.y = v.x + 3.0f * (v.y + v.z) + v.w;
    h.z = v.y + 3.0f * (v.z + v.w) + xp4;
    h.w = v.z + 3.0f * (v.w + xp4) + xp5;
    return h;
}

// Load row y of both planes (and seam fragments), then filter both.
__device__ __forceinline__ void fir_hrow2(const float* __restrict__ pA,
                                          const float* __restrict__ pB,
                                          int y, int lane, int c0,
                                          float4& hA, float4& hB) {
    if ((unsigned)y >= FIR_H) {   // wave-uniform
        hA.x = hA.y = hA.z = hA.w = 0.0f;
        hB = hA;
        return;
    }
    const size_t rowoff = (size_t)y * FIR_W;
    const float* rowA = pA + rowoff;
    const float* rowB = pB + rowoff;
    const float4 vA = *reinterpret_cast<const float4*>(rowA + c0 + 4 * lane);
    const float4 vB = *reinterpret_cast<const float4*>(rowB + c0 + 4 * lane);

    // Seam values from the other half-row (<=1 active lane per plane).
    float4 sA, sB;
    sA.x = sA.y = sA.z = sA.w = 0.0f;
    sB = sA;
    if (lane == 0 && c0 != 0) {
        sA = *reinterpret_cast<const float4*>(rowA + c0 - 4);
        sB = *reinterpret_cast<const float4*>(rowB + c0 - 4);
    }
    if (lane == 63 && c0 == 0) {
        sA = *reinterpret_cast<const float4*>(rowA + 256);
        sB = *reinterpret_cast<const float4*>(rowB + 256);
    }

    hA = fir_hfilt(vA, sA, lane);
    hB = fir_hfilt(vB, sB, lane);
}

__device__ __forceinline__ float4 fir_vcomb(float4 h0, float4 h1, float4 h2, float4 h3) {
    const float s = 1.0f / 64.0f;
    float4 o;
    o.x = (h0.x + h3.x + 3.0f * (h1.x + h2.x)) * s;
    o.y = (h0.y + h3.y + 3.0f * (h1.y + h2.y)) * s;
    o.z = (h0.z + h3.z + 3.0f * (h1.z + h2.z)) * s;
    o.w = (h0.w + h3.w + 3.0f * (h1.w + h2.w)) * s;
    return o;
}

__global__ __launch_bounds__(256, 4) void FIRFilter_88579405512825_kernel(
        const float* __restrict__ x, float* __restrict__ out) {
    const int lane = threadIdx.x;                             // 0..63: 4 cols each
    const int w    = blockIdx.x * blockDim.y + threadIdx.y;   // 0..31: wave task
    const int half  = w & 1;                                  // half-row panel
    const int strip = w >> 1;                                 // 32-row strip
    const int pp    = blockIdx.y;                             // 0..255: plane pair
    const int c0 = half * 256;

    const float* pA = x + (size_t)(2 * pp) * PLANE_SZ;
    const float* pB = pA + PLANE_SZ;
    float* qA = out + (size_t)(2 * pp) * PLANE_SZ;
    float* qB = qA + PLANE_SZ;

    const int r0 = strip * FIR_ROWS;

    // Rolling windows (per plane): need H(r-1..r+2) for output row r.
    float4 a1, a2, a3, b1, b2, b3;
    fir_hrow2(pA, pB, r0 - 1, lane, c0, a1, b1);
    fir_hrow2(pA, pB, r0,     lane, c0, a2, b2);
    fir_hrow2(pA, pB, r0 + 1, lane, c0, a3, b3);

    #pragma unroll 4
    for (int r = r0; r < r0 + FIR_ROWS; ++r) {
        float4 a0 = a1; a1 = a2; a2 = a3;
        float4 b0 = b1; b1 = b2; b2 = b3;
        fir_hrow2(pA, pB, r + 2, lane, c0, a3, b3);

        const size_t off = (size_t)r * FIR_W + c0 + 4 * lane;
        nt_store4(qA + off, fir_vcomb(a0, a1, a2, a3));
        nt_store4(qB + off, fir_vcomb(b0, b1, b2, b3));
    }
}

extern "C" void kernel_launch(void* const* d_in, const int* in_sizes, int n_in,
                              void* d_out, int out_size, void* d_ws, size_t ws_size,
                              hipStream_t stream) {
    const float* x = (const float*)d_in[0];
    float* out = (float*)d_out;

    const int planes = in_sizes[0] / (FIR_W * FIR_H);   // 8*64 = 512

    // block: 64 lanes x 4 waves = 256 threads; 32 wave-tasks per plane-pair
    // (2 half-row panels x 16 strips of 32 rows) -> grid.x = 8.
    dim3 block(64, 4);
    dim3 grid(8, planes / 2);

    FIRFilter_88579405512825_kernel<<<grid, block, 0, stream>>>(x, out);
}